// Round 2
// baseline (428.493 us; speedup 1.0000x reference)
//
#include <hip/hip_runtime.h>

// SpeakerCrossAttention on MI355X (gfx950)  — v2: occupancy-focused
// B=16, D=512, T=8192, S=256. f32 in/out; big GEMM in bf16 MFMA.
//
// v2 changes vs v1 (224us main, 42% occupancy, everything idle):
//  - t-tile 64 -> 32 (grid 4096), LDS 75KB -> ~40.5KB  => 4 blocks/CU by LDS
//  - per-wave GEMM split into 2 passes of 32n x 32t (acc[2][2] = 16 regs,
//    was acc[4][4]=64) so VGPR+ACC fits 64 => 8 waves/SIMD possible
//  - __launch_bounds__(512, 8) to cap regalloc at 64
//  - s_wg2 stored bf16 to fit the 40.96KB LDS budget

typedef __attribute__((ext_vector_type(8))) short  short8;   // 8 bf16 (MFMA A/B frag)
typedef __attribute__((ext_vector_type(4))) unsigned short ushort4v;
typedef __attribute__((ext_vector_type(4))) float  f32x4;

#define T_DIM 8192
#define D_DIM 512
#define KST   520   // LDS row stride (elems); 1040B -> row-to-row bank shift of 16B mod 128B

__device__ __forceinline__ unsigned short f2bf(float x) {  // RTNE f32 -> bf16
  unsigned u = __builtin_bit_cast(unsigned, x);
  u = (u + 0x7fffu + ((u >> 16) & 1u)) >> 16;
  return (unsigned short)u;
}
__device__ __forceinline__ float bf2f(unsigned short h) {
  return __builtin_bit_cast(float, ((unsigned)h) << 16);
}

// ---------------- prep kernel (unchanged from v1) ----------------
__global__ __launch_bounds__(512) void prep_kernel(
    const float* __restrict__ spk_in, const float* __restrict__ Wsp,
    const float* __restrict__ bsp,    const float* __restrict__ Wv,
    const float* __restrict__ bv,     const float* __restrict__ Wo,
    const float* __restrict__ bo,     const float* __restrict__ gma,
    const float* __restrict__ bta,    const float* __restrict__ Wg1,
    const float* __restrict__ bg1,
    float* __restrict__ attnn, float* __restrict__ biasb,
    unsigned short* __restrict__ w1fx)
{
  int tid = threadIdx.x;
  int blk = blockIdx.x;

  if (blk >= 16) {                    // ---- W1f -> bf16 conversion ----
    int base = (blk - 16) * 2048 + tid;
    #pragma unroll
    for (int i = 0; i < 4; ++i) {
      int idx = base + i * 512;       // 128 blocks * 512 thr * 4 = 262144 = 512*512
      int n = idx >> 9, k = idx & 511;
      w1fx[idx] = f2bf(Wg1[n * 1024 + k]);
    }
    return;
  }

  int b = blk;
  __shared__ __attribute__((aligned(16))) float s_spk[256];
  __shared__ __attribute__((aligned(16))) float s_x[512];
  __shared__ __attribute__((aligned(16))) float s_y[512];
  __shared__ float red[512];

  float se = (tid < 256) ? spk_in[b * 256 + tid] : 0.f;
  red[tid] = se * se;
  __syncthreads();
  for (int s = 256; s > 0; s >>= 1) {
    if (tid < s) red[tid] += red[tid + s];
    __syncthreads();
  }
  float scale = 1.f / fmaxf(sqrtf(red[0]), 1e-12f);
  if (tid < 256) s_spk[tid] = se * scale;
  __syncthreads();

  {
    const float* wr = Wsp + (size_t)tid * 256;
    f32x4 a4 = {0.f, 0.f, 0.f, 0.f};
    #pragma unroll 8
    for (int s2 = 0; s2 < 256; s2 += 4)
      a4 += (*(const f32x4*)(wr + s2)) * (*(const f32x4*)(s_spk + s2));
    s_x[tid] = a4[0] + a4[1] + a4[2] + a4[3] + bsp[tid];
  }
  __syncthreads();

  {
    const float* wr = Wv + (size_t)tid * 512;
    f32x4 a4 = {0.f, 0.f, 0.f, 0.f};
    #pragma unroll 8
    for (int s2 = 0; s2 < 512; s2 += 4)
      a4 += (*(const f32x4*)(wr + s2)) * (*(const f32x4*)(s_x + s2));
    s_y[tid] = a4[0] + a4[1] + a4[2] + a4[3] + bv[tid];
  }
  __syncthreads();

  float attnv;
  {
    const float* wr = Wo + (size_t)tid * 512;
    f32x4 a4 = {0.f, 0.f, 0.f, 0.f};
    #pragma unroll 8
    for (int s2 = 0; s2 < 512; s2 += 4)
      a4 += (*(const f32x4*)(wr + s2)) * (*(const f32x4*)(s_y + s2));
    attnv = a4[0] + a4[1] + a4[2] + a4[3] + bo[tid];
  }

  red[tid] = attnv;
  __syncthreads();
  for (int s = 256; s > 0; s >>= 1) {
    if (tid < s) red[tid] += red[tid + s];
    __syncthreads();
  }
  float mu = red[0] * (1.f / 512.f);
  __syncthreads();
  float dv = attnv - mu;
  red[tid] = dv * dv;
  __syncthreads();
  for (int s = 256; s > 0; s >>= 1) {
    if (tid < s) red[tid] += red[tid + s];
    __syncthreads();
  }
  float var = red[0] * (1.f / 512.f);
  float an = dv * rsqrtf(var + 1e-5f) * gma[tid] + bta[tid];
  s_x[tid] = an;
  attnn[b * 512 + tid] = an;
  __syncthreads();

  {
    const float* wr = Wg1 + (size_t)tid * 1024 + 512;
    f32x4 a4 = {0.f, 0.f, 0.f, 0.f};
    #pragma unroll 8
    for (int s2 = 0; s2 < 512; s2 += 4)
      a4 += (*(const f32x4*)(wr + s2)) * (*(const f32x4*)(s_x + s2));
    biasb[b * 512 + tid] = a4[0] + a4[1] + a4[2] + a4[3] + bg1[tid];
  }
}

// ---------------- main kernel ----------------
__global__ __launch_bounds__(512, 8) void main_kernel(
    const float* __restrict__ feat, const unsigned short* __restrict__ w1fx,
    const float* __restrict__ attnn, const float* __restrict__ biasb,
    const float* __restrict__ wg2p,  const float* __restrict__ bg2p,
    float* __restrict__ out)
{
  __shared__ __attribute__((aligned(16))) unsigned short S[32 * KST];   // 33280 B
  __shared__ __attribute__((aligned(16))) float s_attn[512];            // 2048
  __shared__ __attribute__((aligned(16))) float s_bias[512];            // 2048
  __shared__ __attribute__((aligned(8)))  unsigned short s_wg2[512];    // 1024
  __shared__ float s_gpart[8 * 32];                                     // 1024
  __shared__ float s_alpha[32];                                         // 128

  int tid = threadIdx.x;
  int b  = blockIdx.x >> 8;
  int t0 = (blockIdx.x & 255) << 5;
  const float* fb = feat + ((size_t)b * D_DIM) * T_DIM + t0;

  // ---- stage features tile (32 t x 512 k) -> bf16 LDS [t][k] ----
  {
    int mt = tid & 7;           // t-chunk (4 t each), 0..7
    int mk = tid >> 3;          // k-quad (4 k each), 0..63
    int tt = mt * 4;
    #pragma unroll
    for (int it = 0; it < 2; ++it) {
      int k0 = (mk + it * 64) * 4;
      f32x4 r0 = *(const f32x4*)(fb + (size_t)(k0 + 0) * T_DIM + tt);
      f32x4 r1 = *(const f32x4*)(fb + (size_t)(k0 + 1) * T_DIM + tt);
      f32x4 r2 = *(const f32x4*)(fb + (size_t)(k0 + 2) * T_DIM + tt);
      f32x4 r3 = *(const f32x4*)(fb + (size_t)(k0 + 3) * T_DIM + tt);
      #pragma unroll
      for (int i = 0; i < 4; ++i) {
        ushort4v wv;
        wv[0] = f2bf(r0[i]); wv[1] = f2bf(r1[i]);
        wv[2] = f2bf(r2[i]); wv[3] = f2bf(r3[i]);
        *(ushort4v*)(&S[(tt + i) * KST + k0]) = wv;   // ds_write_b64, transposed
      }
    }
    s_attn[tid] = attnn[b * 512 + tid];
    s_bias[tid] = biasb[b * 512 + tid];
    s_wg2[tid]  = f2bf(wg2p[tid]);
  }
  __syncthreads();

  // ---- GEMM: h^T = W1f * F^T ; wave w owns n in [64w,64w+64), t in [0,32)
  //      two passes of 32n x 32t so acc is only 16 regs ----
  int l = tid & 63, w = tid >> 6;
  int g = l >> 4, c = l & 15;
  int n0w = w * 64;

  const unsigned short* bp0 = &S[c * KST + g * 8];

  float p0 = 0.f, p1 = 0.f;      // alpha partials for t=c and t=16+c

  #pragma unroll
  for (int half = 0; half < 2; ++half) {
    int nbase = n0w + 32 * half;
    f32x4 acc[2][2];
    #pragma unroll
    for (int i = 0; i < 2; ++i)
      #pragma unroll
      for (int j = 0; j < 2; ++j)
        acc[i][j] = (f32x4){0.f, 0.f, 0.f, 0.f};

    const unsigned short* ap0 = w1fx + (size_t)(nbase + c) * 512 + g * 8;

    #pragma unroll 4
    for (int kk = 0; kk < 16; ++kk) {
      short8 af[2], bf[2];
      #pragma unroll
      for (int ni = 0; ni < 2; ++ni)
        af[ni] = *(const short8*)(ap0 + ni * (16 * 512) + kk * 32);
      #pragma unroll
      for (int tg = 0; tg < 2; ++tg)
        bf[tg] = *(const short8*)(bp0 + tg * (16 * KST) + kk * 32);
      #pragma unroll
      for (int ni = 0; ni < 2; ++ni)
        #pragma unroll
        for (int tg = 0; tg < 2; ++tg)
          acc[ni][tg] = __builtin_amdgcn_mfma_f32_16x16x32_bf16(
              af[ni], bf[tg], acc[ni][tg], 0, 0, 0);
    }
    // lane l, reg r of acc[ni][tg]: h[n = nbase+16ni+4g+r][t = 16tg+c]
    #pragma unroll
    for (int ni = 0; ni < 2; ++ni) {
      #pragma unroll
      for (int r = 0; r < 4; ++r) {
        int n = nbase + 16 * ni + 4 * g + r;
        float bb = s_bias[n], ww = bf2f(s_wg2[n]);
        p0 += fmaxf(acc[ni][0][r] + bb, 0.f) * ww;
        p1 += fmaxf(acc[ni][1][r] + bb, 0.f) * ww;
      }
    }
  }

  // ---- alpha: reduce over n across lanes then waves ----
  p0 += __shfl_xor(p0, 16); p0 += __shfl_xor(p0, 32);
  p1 += __shfl_xor(p1, 16); p1 += __shfl_xor(p1, 32);
  if (l < 16) {
    s_gpart[w * 32 +  0 + l] = p0;
    s_gpart[w * 32 + 16 + l] = p1;
  }
  __syncthreads();
  if (tid < 32) {
    float gs = bg2p[0];
    #pragma unroll
    for (int w2 = 0; w2 < 8; ++w2) gs += s_gpart[w2 * 32 + tid];
    s_alpha[tid] = 1.f / (1.f + expf(-gs));
  }
  __syncthreads();

  // ---- blend + store: out[b,n,t0+t] = a*f + (1-a)*attn_n[n] ----
  {
    int t = tid & 31, ng = tid >> 5;      // ng 0..15
    float al = s_alpha[t], om = 1.f - al;
    float* ob = out + ((size_t)b * D_DIM) * T_DIM + t0 + t;
    const unsigned short* srow = &S[t * KST];
    #pragma unroll 4
    for (int it = 0; it < 8; ++it) {
      int n0 = it * 64 + ng * 4;
      ushort4v fv = *(const ushort4v*)(srow + n0);
      f32x4 an = *(const f32x4*)(&s_attn[n0]);
      #pragma unroll
      for (int i = 0; i < 4; ++i)
        ob[(size_t)(n0 + i) * T_DIM] = al * bf2f(fv[i]) + om * an[i];
    }
  }
}

extern "C" void kernel_launch(void* const* d_in, const int* in_sizes, int n_in,
                              void* d_out, int out_size, void* d_ws, size_t ws_size,
                              hipStream_t stream) {
  const float* features = (const float*)d_in[0];
  const float* spk      = (const float*)d_in[1];
  const float* Wsp      = (const float*)d_in[2];
  const float* bsp      = (const float*)d_in[3];
  const float* Wv       = (const float*)d_in[4];
  const float* bv       = (const float*)d_in[5];
  const float* Wo       = (const float*)d_in[6];
  const float* bo       = (const float*)d_in[7];
  const float* gma      = (const float*)d_in[8];
  const float* bta      = (const float*)d_in[9];
  const float* Wg1      = (const float*)d_in[10];
  const float* bg1      = (const float*)d_in[11];
  const float* Wg2      = (const float*)d_in[12];
  const float* bg2      = (const float*)d_in[13];
  float* out = (float*)d_out;

  float* attnn = (float*)d_ws;
  float* biasb = attnn + 16 * 512;
  unsigned short* w1fx = (unsigned short*)(biasb + 16 * 512);

  prep_kernel<<<144, 512, 0, stream>>>(spk, Wsp, bsp, Wv, bv, Wo, bo, gma, bta,
                                       Wg1, bg1, attnn, biasb, w1fx);
  main_kernel<<<4096, 512, 0, stream>>>(features, w1fx, attnn, biasb, Wg2, bg2, out);
}

// Round 3
// 365.126 us; speedup vs baseline: 1.1735x; 1.1735x over previous
//
#include <hip/hip_runtime.h>

// SpeakerCrossAttention on MI355X (gfx950) — v3: persistent double-buffered pipeline
// B=16, D=512, T=8192, S=256. f32 in/out; big GEMM in bf16 MFMA.
//
// v3 vs v1 (224us main; all pipes idle -> latency/serial-phase bound):
//  - 256 persistent blocks (1/CU), 512 thr, each does 8 tiles of 64t (one b each)
//  - double-buffered LDS staging: issue tile j+1's global loads before computing
//    tile j  => HBM read/write streams continuously instead of bursting
//  - per-batch prep chain folded into block prologue (hidden under first loads);
//    prep kernel reduced to W1f->bf16 conversion only
//  - __launch_bounds__(512,2): 256-reg budget for 64 staged f32x4 + 64 acc

typedef __attribute__((ext_vector_type(8))) short short8;     // 8 bf16 (MFMA A/B frag)
typedef __attribute__((ext_vector_type(4))) unsigned short ushort4v;
typedef __attribute__((ext_vector_type(4))) float f32x4;

#define T_DIM 8192
#define D_DIM 512
#define KST   520      // LDS row stride (elems); rows 16B-aligned
#define NT    8        // tiles per block

__device__ __forceinline__ unsigned short f2bf(float x) {  // RTNE f32 -> bf16
  unsigned u = __builtin_bit_cast(unsigned, x);
  u = (u + 0x7fffu + ((u >> 16) & 1u)) >> 16;
  return (unsigned short)u;
}
__device__ __forceinline__ float bf2f(unsigned short h) {
  return __builtin_bit_cast(float, ((unsigned)h) << 16);
}

// ---------------- W1f bf16 conversion ----------------
__global__ __launch_bounds__(512) void conv_kernel(const float* __restrict__ Wg1,
                                                   unsigned short* __restrict__ w1fx) {
  int base = blockIdx.x * 2048 + threadIdx.x;
  #pragma unroll
  for (int i = 0; i < 4; ++i) {
    int idx = base + i * 512;            // 128 blocks * 512 thr * 4 = 512*512
    int n = idx >> 9, k = idx & 511;
    w1fx[idx] = f2bf(Wg1[n * 1024 + k]);
  }
}

// ---------------- main persistent kernel ----------------
__global__ __launch_bounds__(512, 2) void main_kernel(
    const float* __restrict__ feat, const unsigned short* __restrict__ w1fx,
    const float* __restrict__ spk_in, const float* __restrict__ Wsp,
    const float* __restrict__ bsp,    const float* __restrict__ Wv,
    const float* __restrict__ bv,     const float* __restrict__ Wo,
    const float* __restrict__ bo,     const float* __restrict__ gma,
    const float* __restrict__ bta,    const float* __restrict__ Wg1,
    const float* __restrict__ bg1,    const float* __restrict__ Wg2,
    const float* __restrict__ bg2,    float* __restrict__ out)
{
  __shared__ __attribute__((aligned(16))) unsigned short S0[64 * KST]; // 66560 B
  __shared__ __attribute__((aligned(16))) unsigned short S1[64 * KST]; // 66560 B
  __shared__ __attribute__((aligned(16))) float s_attn[512];
  __shared__ __attribute__((aligned(16))) float s_bias[512];
  __shared__ __attribute__((aligned(16))) float s_wg2[512];
  __shared__ __attribute__((aligned(16))) float s_spk[256];
  __shared__ __attribute__((aligned(16))) float red[512];
  __shared__ float s_gpart[8 * 64];
  __shared__ float s_alpha[64];

  int tid = threadIdx.x;
  int b      = blockIdx.x >> 4;          // 16 blocks per batch row
  int t0base = (blockIdx.x & 15) << 9;   // * 512  (8 tiles of 64 t)

  const float* fbase = feat + (size_t)b * D_DIM * T_DIM + t0base;
  float*       obase = out  + (size_t)b * D_DIM * T_DIM + t0base;

  int mt = tid & 15, mk = tid >> 4;      // stage mapping
  int tt = mt * 4;

  f32x4 ra[16], rb[16];

#define ISSUE(J, RR) do {                                                  \
    const float* fb_ = fbase + (J) * 64 + tt;                              \
    _Pragma("unroll")                                                      \
    for (int it_ = 0; it_ < 4; ++it_) {                                    \
      int k0_ = (mk + it_ * 32) * 4;                                       \
      _Pragma("unroll")                                                    \
      for (int q_ = 0; q_ < 4; ++q_)                                       \
        RR[it_ * 4 + q_] = *(const f32x4*)(fb_ + (size_t)(k0_ + q_) * T_DIM); \
    }                                                                      \
  } while (0)

#define COMMIT(RR, SB) do {                                                \
    _Pragma("unroll")                                                      \
    for (int it_ = 0; it_ < 4; ++it_) {                                    \
      int k0_ = (mk + it_ * 32) * 4;                                       \
      _Pragma("unroll")                                                    \
      for (int i_ = 0; i_ < 4; ++i_) {                                     \
        ushort4v wv_;                                                      \
        wv_[0] = f2bf(RR[it_*4+0][i_]); wv_[1] = f2bf(RR[it_*4+1][i_]);    \
        wv_[2] = f2bf(RR[it_*4+2][i_]); wv_[3] = f2bf(RR[it_*4+3][i_]);    \
        *(ushort4v*)(&(SB)[(tt + i_) * KST + k0_]) = wv_;                  \
      }                                                                    \
    }                                                                      \
  } while (0)

  // ---- prologue: issue first tile's loads, then per-batch chain (hides latency)
  ISSUE(0, ra);

  float bg2v = bg2[0];
  {
    float se = (tid < 256) ? spk_in[b * 256 + tid] : 0.f;
    red[tid] = se * se;
    __syncthreads();
    for (int s = 256; s > 0; s >>= 1) {
      if (tid < s) red[tid] += red[tid + s];
      __syncthreads();
    }
    float scale = 1.f / fmaxf(sqrtf(red[0]), 1e-12f);
    if (tid < 256) s_spk[tid] = se * scale;
    __syncthreads();

    {  // sf -> s_attn
      const float* wr = Wsp + (size_t)tid * 256;
      f32x4 a4 = {0.f, 0.f, 0.f, 0.f};
      #pragma unroll 8
      for (int s2 = 0; s2 < 256; s2 += 4)
        a4 += (*(const f32x4*)(wr + s2)) * (*(const f32x4*)(s_spk + s2));
      s_attn[tid] = a4[0] + a4[1] + a4[2] + a4[3] + bsp[tid];
    }
    __syncthreads();
    {  // v -> s_bias
      const float* wr = Wv + (size_t)tid * 512;
      f32x4 a4 = {0.f, 0.f, 0.f, 0.f};
      #pragma unroll 8
      for (int s2 = 0; s2 < 512; s2 += 4)
        a4 += (*(const f32x4*)(wr + s2)) * (*(const f32x4*)(s_attn + s2));
      s_bias[tid] = a4[0] + a4[1] + a4[2] + a4[3] + bv[tid];
    }
    __syncthreads();
    float attnv;
    {  // attn
      const float* wr = Wo + (size_t)tid * 512;
      f32x4 a4 = {0.f, 0.f, 0.f, 0.f};
      #pragma unroll 8
      for (int s2 = 0; s2 < 512; s2 += 4)
        a4 += (*(const f32x4*)(wr + s2)) * (*(const f32x4*)(s_bias + s2));
      attnv = a4[0] + a4[1] + a4[2] + a4[3] + bo[tid];
    }
    red[tid] = attnv;
    __syncthreads();
    for (int s = 256; s > 0; s >>= 1) {
      if (tid < s) red[tid] += red[tid + s];
      __syncthreads();
    }
    float mu = red[0] * (1.f / 512.f);
    __syncthreads();                       // all have mu before red reuse
    float dvv = attnv - mu;
    red[tid] = dvv * dvv;
    __syncthreads();
    for (int s = 256; s > 0; s >>= 1) {
      if (tid < s) red[tid] += red[tid + s];
      __syncthreads();
    }
    float var = red[0] * (1.f / 512.f);
    float an = dvv * rsqrtf(var + 1e-5f) * gma[tid] + bta[tid];
    __syncthreads();                       // all reads of old s_attn done
    s_attn[tid] = an;
    __syncthreads();
    {  // bias_b -> s_bias  (W1a = Wg1[:, 512:])
      const float* wr = Wg1 + (size_t)tid * 1024 + 512;
      f32x4 a4 = {0.f, 0.f, 0.f, 0.f};
      #pragma unroll 8
      for (int s2 = 0; s2 < 512; s2 += 4)
        a4 += (*(const f32x4*)(wr + s2)) * (*(const f32x4*)(s_attn + s2));
      s_bias[tid] = a4[0] + a4[1] + a4[2] + a4[3] + bg1[tid];
    }
    s_wg2[tid] = Wg2[tid];
    // visibility of s_bias/s_wg2: covered by the barrier before first COMPUTE
  }

  // ---- GEMM lane mapping (v1-verified) ----
  int l = tid & 63, w = tid >> 6;
  int g = l >> 4, c = l & 15;
  int n0w = w * 64;
  const unsigned short* ap0 = w1fx + (size_t)(n0w + c) * 512 + g * 8;

#define COMPUTE(SB, J) do {                                                 \
    const unsigned short* bp0_ = &(SB)[c * KST + g * 8];                    \
    f32x4 acc[4][4];                                                        \
    _Pragma("unroll")                                                       \
    for (int i_ = 0; i_ < 4; ++i_)                                          \
      _Pragma("unroll")                                                     \
      for (int j_ = 0; j_ < 4; ++j_)                                        \
        acc[i_][j_] = (f32x4){0.f, 0.f, 0.f, 0.f};                          \
    _Pragma("unroll 2")                                                     \
    for (int kk = 0; kk < 16; ++kk) {                                       \
      short8 af[4], bf[4];                                                  \
      _Pragma("unroll")                                                     \
      for (int ni = 0; ni < 4; ++ni)                                        \
        af[ni] = *(const short8*)(ap0 + ni * (16 * 512) + kk * 32);         \
      _Pragma("unroll")                                                     \
      for (int tg = 0; tg < 4; ++tg)                                        \
        bf[tg] = *(const short8*)(bp0_ + tg * (16 * KST) + kk * 32);        \
      _Pragma("unroll")                                                     \
      for (int ni = 0; ni < 4; ++ni)                                        \
        _Pragma("unroll")                                                   \
        for (int tg = 0; tg < 4; ++tg)                                      \
          acc[ni][tg] = __builtin_amdgcn_mfma_f32_16x16x32_bf16(            \
              af[ni], bf[tg], acc[ni][tg], 0, 0, 0);                        \
    }                                                                       \
    float p0 = 0.f, p1 = 0.f, p2 = 0.f, p3 = 0.f;                           \
    _Pragma("unroll")                                                       \
    for (int ni = 0; ni < 4; ++ni) {                                        \
      _Pragma("unroll")                                                     \
      for (int r_ = 0; r_ < 4; ++r_) {                                      \
        int n_ = n0w + 16 * ni + 4 * g + r_;                                \
        float bb_ = s_bias[n_], ww_ = s_wg2[n_];                            \
        p0 += fmaxf(acc[ni][0][r_] + bb_, 0.f) * ww_;                       \
        p1 += fmaxf(acc[ni][1][r_] + bb_, 0.f) * ww_;                       \
        p2 += fmaxf(acc[ni][2][r_] + bb_, 0.f) * ww_;                       \
        p3 += fmaxf(acc[ni][3][r_] + bb_, 0.f) * ww_;                       \
      }                                                                     \
    }                                                                       \
    p0 += __shfl_xor(p0, 16); p0 += __shfl_xor(p0, 32);                     \
    p1 += __shfl_xor(p1, 16); p1 += __shfl_xor(p1, 32);                     \
    p2 += __shfl_xor(p2, 16); p2 += __shfl_xor(p2, 32);                     \
    p3 += __shfl_xor(p3, 16); p3 += __shfl_xor(p3, 32);                     \
    if (l < 16) {                                                           \
      s_gpart[w * 64 +  0 + l] = p0;                                        \
      s_gpart[w * 64 + 16 + l] = p1;                                        \
      s_gpart[w * 64 + 32 + l] = p2;                                        \
      s_gpart[w * 64 + 48 + l] = p3;                                        \
    }                                                                       \
    __syncthreads();                                                        \
    if (tid < 64) {                                                         \
      float gs = bg2v;                                                      \
      _Pragma("unroll")                                                     \
      for (int w2 = 0; w2 < 8; ++w2) gs += s_gpart[w2 * 64 + tid];          \
      s_alpha[tid] = 1.f / (1.f + expf(-gs));                               \
    }                                                                       \
    __syncthreads();                                                        \
    {                                                                       \
      int tl_ = tid & 63, gg_ = tid >> 6;                                   \
      float al_ = s_alpha[tl_], om_ = 1.f - al_;                            \
      float* ob_ = obase + (J) * 64 + tl_;                                  \
      const unsigned short* srow_ = &(SB)[tl_ * KST];                       \
      _Pragma("unroll 4")                                                   \
      for (int it_ = 0; it_ < 16; ++it_) {                                  \
        int n0_ = it_ * 32 + gg_ * 4;                                       \
        ushort4v fv_ = *(const ushort4v*)(srow_ + n0_);                     \
        f32x4 an_ = *(const f32x4*)(&s_attn[n0_]);                          \
        _Pragma("unroll")                                                   \
        for (int i_ = 0; i_ < 4; ++i_)                                      \
          ob_[(size_t)(n0_ + i_) * T_DIM] = al_ * bf2f(fv_[i_]) + om_ * an_[i_]; \
      }                                                                     \
    }                                                                       \
  } while (0)

  // ---- pipelined tile loop: 2 tiles per iteration, static buffers/regs ----
  #pragma unroll 1
  for (int jj = 0; jj < NT; jj += 2) {
    COMMIT(ra, S0);
    ISSUE(jj + 1, rb);          // next tile's loads in flight during COMPUTE
    __syncthreads();            // staging of S0 visible
    COMPUTE(S0, jj);

    COMMIT(rb, S1);
    if (jj + 2 < NT) ISSUE(jj + 2, ra);
    __syncthreads();            // staging of S1 visible
    COMPUTE(S1, jj + 1);
  }
#undef ISSUE
#undef COMMIT
#undef COMPUTE
}

extern "C" void kernel_launch(void* const* d_in, const int* in_sizes, int n_in,
                              void* d_out, int out_size, void* d_ws, size_t ws_size,
                              hipStream_t stream) {
  const float* features = (const float*)d_in[0];
  const float* spk      = (const float*)d_in[1];
  const float* Wsp      = (const float*)d_in[2];
  const float* bsp      = (const float*)d_in[3];
  const float* Wv       = (const float*)d_in[4];
  const float* bv       = (const float*)d_in[5];
  const float* Wo       = (const float*)d_in[6];
  const float* bo       = (const float*)d_in[7];
  const float* gma      = (const float*)d_in[8];
  const float* bta      = (const float*)d_in[9];
  const float* Wg1      = (const float*)d_in[10];
  const float* bg1      = (const float*)d_in[11];
  const float* Wg2      = (const float*)d_in[12];
  const float* bg2      = (const float*)d_in[13];
  float* out = (float*)d_out;

  unsigned short* w1fx = (unsigned short*)d_ws;   // 512x512 bf16 = 512 KB

  conv_kernel<<<128, 512, 0, stream>>>(Wg1, w1fx);
  main_kernel<<<256, 512, 0, stream>>>(features, w1fx, spk, Wsp, bsp, Wv, bv,
                                       Wo, bo, gma, bta, Wg1, bg1, Wg2, bg2, out);
}

// Round 4
// 362.419 us; speedup vs baseline: 1.1823x; 1.0075x over previous
//
#include <hip/hip_runtime.h>

// SpeakerCrossAttention on MI355X (gfx950) — v4: persistent double-buffered pipeline,
// register-budget fix.
// B=16, D=512, T=8192, S=256. f32 in/out; big GEMM in bf16 MFMA.
//
// v4 vs v3 (382us, 48us/tile):
//  - __launch_bounds__(512) with NO min-waves arg: v3's (512,2) capped arch-VGPRs
//    at 128 < ~190 live => staged prefetch arrays were rematerialized/spilled,
//    killing the pipeline. Now the 8-wave block's natural cap (256) applies.
//  - ISSUE(j+1) moved BEFORE COMMIT(j): next tile's reads in flight during the
//    f2bf+ds_write commit work as well as during COMPUTE.

typedef __attribute__((ext_vector_type(8))) short short8;     // 8 bf16 (MFMA A/B frag)
typedef __attribute__((ext_vector_type(4))) unsigned short ushort4v;
typedef __attribute__((ext_vector_type(4))) float f32x4;

#define T_DIM 8192
#define D_DIM 512
#define KST   520      // LDS row stride (elems); rows 16B-aligned
#define NT    8        // tiles per block

__device__ __forceinline__ unsigned short f2bf(float x) {  // RTNE f32 -> bf16
  unsigned u = __builtin_bit_cast(unsigned, x);
  u = (u + 0x7fffu + ((u >> 16) & 1u)) >> 16;
  return (unsigned short)u;
}
__device__ __forceinline__ float bf2f(unsigned short h) {
  return __builtin_bit_cast(float, ((unsigned)h) << 16);
}

// ---------------- W1f bf16 conversion ----------------
__global__ __launch_bounds__(512) void conv_kernel(const float* __restrict__ Wg1,
                                                   unsigned short* __restrict__ w1fx) {
  int base = blockIdx.x * 2048 + threadIdx.x;
  #pragma unroll
  for (int i = 0; i < 4; ++i) {
    int idx = base + i * 512;            // 128 blocks * 512 thr * 4 = 512*512
    int n = idx >> 9, k = idx & 511;
    w1fx[idx] = f2bf(Wg1[n * 1024 + k]);
  }
}

// ---------------- main persistent kernel ----------------
__global__ __launch_bounds__(512) void main_kernel(
    const float* __restrict__ feat, const unsigned short* __restrict__ w1fx,
    const float* __restrict__ spk_in, const float* __restrict__ Wsp,
    const float* __restrict__ bsp,    const float* __restrict__ Wv,
    const float* __restrict__ bv,     const float* __restrict__ Wo,
    const float* __restrict__ bo,     const float* __restrict__ gma,
    const float* __restrict__ bta,    const float* __restrict__ Wg1,
    const float* __restrict__ bg1,    const float* __restrict__ Wg2,
    const float* __restrict__ bg2,    float* __restrict__ out)
{
  __shared__ __attribute__((aligned(16))) unsigned short S0[64 * KST]; // 66560 B
  __shared__ __attribute__((aligned(16))) unsigned short S1[64 * KST]; // 66560 B
  __shared__ __attribute__((aligned(16))) float s_attn[512];
  __shared__ __attribute__((aligned(16))) float s_bias[512];
  __shared__ __attribute__((aligned(16))) float s_wg2[512];
  __shared__ __attribute__((aligned(16))) float s_spk[256];
  __shared__ __attribute__((aligned(16))) float red[512];
  __shared__ float s_gpart[8 * 64];
  __shared__ float s_alpha[64];

  int tid = threadIdx.x;
  int b      = blockIdx.x >> 4;          // 16 blocks per batch row
  int t0base = (blockIdx.x & 15) << 9;   // * 512  (8 tiles of 64 t)

  const float* fbase = feat + (size_t)b * D_DIM * T_DIM + t0base;
  float*       obase = out  + (size_t)b * D_DIM * T_DIM + t0base;

  int mt = tid & 15, mk = tid >> 4;      // stage mapping
  int tt = mt * 4;

  f32x4 ra[16], rb[16];

#define ISSUE(J, RR) do {                                                  \
    const float* fb_ = fbase + (J) * 64 + tt;                              \
    _Pragma("unroll")                                                      \
    for (int it_ = 0; it_ < 4; ++it_) {                                    \
      int k0_ = (mk + it_ * 32) * 4;                                       \
      _Pragma("unroll")                                                    \
      for (int q_ = 0; q_ < 4; ++q_)                                       \
        RR[it_ * 4 + q_] = *(const f32x4*)(fb_ + (size_t)(k0_ + q_) * T_DIM); \
    }                                                                      \
  } while (0)

#define COMMIT(RR, SB) do {                                                \
    _Pragma("unroll")                                                      \
    for (int it_ = 0; it_ < 4; ++it_) {                                    \
      int k0_ = (mk + it_ * 32) * 4;                                       \
      _Pragma("unroll")                                                    \
      for (int i_ = 0; i_ < 4; ++i_) {                                     \
        ushort4v wv_;                                                      \
        wv_[0] = f2bf(RR[it_*4+0][i_]); wv_[1] = f2bf(RR[it_*4+1][i_]);    \
        wv_[2] = f2bf(RR[it_*4+2][i_]); wv_[3] = f2bf(RR[it_*4+3][i_]);    \
        *(ushort4v*)(&(SB)[(tt + i_) * KST + k0_]) = wv_;                  \
      }                                                                    \
    }                                                                      \
  } while (0)

  // ---- prologue: issue first tile's loads, then per-batch chain (hides latency)
  ISSUE(0, ra);

  float bg2v = bg2[0];
  {
    float se = (tid < 256) ? spk_in[b * 256 + tid] : 0.f;
    red[tid] = se * se;
    __syncthreads();
    for (int s = 256; s > 0; s >>= 1) {
      if (tid < s) red[tid] += red[tid + s];
      __syncthreads();
    }
    float scale = 1.f / fmaxf(sqrtf(red[0]), 1e-12f);
    if (tid < 256) s_spk[tid] = se * scale;
    __syncthreads();

    {  // sf -> s_attn
      const float* wr = Wsp + (size_t)tid * 256;
      f32x4 a4 = {0.f, 0.f, 0.f, 0.f};
      #pragma unroll 8
      for (int s2 = 0; s2 < 256; s2 += 4)
        a4 += (*(const f32x4*)(wr + s2)) * (*(const f32x4*)(s_spk + s2));
      s_attn[tid] = a4[0] + a4[1] + a4[2] + a4[3] + bsp[tid];
    }
    __syncthreads();
    {  // v -> s_bias
      const float* wr = Wv + (size_t)tid * 512;
      f32x4 a4 = {0.f, 0.f, 0.f, 0.f};
      #pragma unroll 8
      for (int s2 = 0; s2 < 512; s2 += 4)
        a4 += (*(const f32x4*)(wr + s2)) * (*(const f32x4*)(s_attn + s2));
      s_bias[tid] = a4[0] + a4[1] + a4[2] + a4[3] + bv[tid];
    }
    __syncthreads();
    float attnv;
    {  // attn
      const float* wr = Wo + (size_t)tid * 512;
      f32x4 a4 = {0.f, 0.f, 0.f, 0.f};
      #pragma unroll 8
      for (int s2 = 0; s2 < 512; s2 += 4)
        a4 += (*(const f32x4*)(wr + s2)) * (*(const f32x4*)(s_bias + s2));
      attnv = a4[0] + a4[1] + a4[2] + a4[3] + bo[tid];
    }
    red[tid] = attnv;
    __syncthreads();
    for (int s = 256; s > 0; s >>= 1) {
      if (tid < s) red[tid] += red[tid + s];
      __syncthreads();
    }
    float mu = red[0] * (1.f / 512.f);
    __syncthreads();                       // all have mu before red reuse
    float dvv = attnv - mu;
    red[tid] = dvv * dvv;
    __syncthreads();
    for (int s = 256; s > 0; s >>= 1) {
      if (tid < s) red[tid] += red[tid + s];
      __syncthreads();
    }
    float var = red[0] * (1.f / 512.f);
    float an = dvv * rsqrtf(var + 1e-5f) * gma[tid] + bta[tid];
    __syncthreads();                       // all reads of old s_attn done
    s_attn[tid] = an;
    __syncthreads();
    {  // bias_b -> s_bias  (W1a = Wg1[:, 512:])
      const float* wr = Wg1 + (size_t)tid * 1024 + 512;
      f32x4 a4 = {0.f, 0.f, 0.f, 0.f};
      #pragma unroll 8
      for (int s2 = 0; s2 < 512; s2 += 4)
        a4 += (*(const f32x4*)(wr + s2)) * (*(const f32x4*)(s_attn + s2));
      s_bias[tid] = a4[0] + a4[1] + a4[2] + a4[3] + bg1[tid];
    }
    s_wg2[tid] = Wg2[tid];
    // visibility of s_bias/s_wg2: covered by the barrier before first COMPUTE
  }

  // ---- GEMM lane mapping (v1-verified) ----
  int l = tid & 63, w = tid >> 6;
  int g = l >> 4, c = l & 15;
  int n0w = w * 64;
  const unsigned short* ap0 = w1fx + (size_t)(n0w + c) * 512 + g * 8;

#define COMPUTE(SB, J) do {                                                 \
    const unsigned short* bp0_ = &(SB)[c * KST + g * 8];                    \
    f32x4 acc[4][4];                                                        \
    _Pragma("unroll")                                                       \
    for (int i_ = 0; i_ < 4; ++i_)                                          \
      _Pragma("unroll")                                                     \
      for (int j_ = 0; j_ < 4; ++j_)                                        \
        acc[i_][j_] = (f32x4){0.f, 0.f, 0.f, 0.f};                          \
    _Pragma("unroll 2")                                                     \
    for (int kk = 0; kk < 16; ++kk) {                                       \
      short8 af[4], bf[4];                                                  \
      _Pragma("unroll")                                                     \
      for (int ni = 0; ni < 4; ++ni)                                        \
        af[ni] = *(const short8*)(ap0 + ni * (16 * 512) + kk * 32);         \
      _Pragma("unroll")                                                     \
      for (int tg = 0; tg < 4; ++tg)                                        \
        bf[tg] = *(const short8*)(bp0_ + tg * (16 * KST) + kk * 32);        \
      _Pragma("unroll")                                                     \
      for (int ni = 0; ni < 4; ++ni)                                        \
        _Pragma("unroll")                                                   \
        for (int tg = 0; tg < 4; ++tg)                                      \
          acc[ni][tg] = __builtin_amdgcn_mfma_f32_16x16x32_bf16(            \
              af[ni], bf[tg], acc[ni][tg], 0, 0, 0);                        \
    }                                                                       \
    float p0 = 0.f, p1 = 0.f, p2 = 0.f, p3 = 0.f;                           \
    _Pragma("unroll")                                                       \
    for (int ni = 0; ni < 4; ++ni) {                                        \
      _Pragma("unroll")                                                     \
      for (int r_ = 0; r_ < 4; ++r_) {                                      \
        int n_ = n0w + 16 * ni + 4 * g + r_;                                \
        float bb_ = s_bias[n_], ww_ = s_wg2[n_];                            \
        p0 += fmaxf(acc[ni][0][r_] + bb_, 0.f) * ww_;                       \
        p1 += fmaxf(acc[ni][1][r_] + bb_, 0.f) * ww_;                       \
        p2 += fmaxf(acc[ni][2][r_] + bb_, 0.f) * ww_;                       \
        p3 += fmaxf(acc[ni][3][r_] + bb_, 0.f) * ww_;                       \
      }                                                                     \
    }                                                                       \
    p0 += __shfl_xor(p0, 16); p0 += __shfl_xor(p0, 32);                     \
    p1 += __shfl_xor(p1, 16); p1 += __shfl_xor(p1, 32);                     \
    p2 += __shfl_xor(p2, 16); p2 += __shfl_xor(p2, 32);                     \
    p3 += __shfl_xor(p3, 16); p3 += __shfl_xor(p3, 32);                     \
    if (l < 16) {                                                           \
      s_gpart[w * 64 +  0 + l] = p0;                                        \
      s_gpart[w * 64 + 16 + l] = p1;                                        \
      s_gpart[w * 64 + 32 + l] = p2;                                        \
      s_gpart[w * 64 + 48 + l] = p3;                                        \
    }                                                                       \
    __syncthreads();                                                        \
    if (tid < 64) {                                                         \
      float gs = bg2v;                                                      \
      _Pragma("unroll")                                                     \
      for (int w2 = 0; w2 < 8; ++w2) gs += s_gpart[w2 * 64 + tid];          \
      s_alpha[tid] = 1.f / (1.f + expf(-gs));                               \
    }                                                                       \
    __syncthreads();                                                        \
    {                                                                       \
      int tl_ = tid & 63, gg_ = tid >> 6;                                   \
      float al_ = s_alpha[tl_], om_ = 1.f - al_;                            \
      float* ob_ = obase + (J) * 64 + tl_;                                  \
      const unsigned short* srow_ = &(SB)[tl_ * KST];                       \
      _Pragma("unroll 4")                                                   \
      for (int it_ = 0; it_ < 16; ++it_) {                                  \
        int n0_ = it_ * 32 + gg_ * 4;                                       \
        ushort4v fv_ = *(const ushort4v*)(srow_ + n0_);                     \
        f32x4 an_ = *(const f32x4*)(&s_attn[n0_]);                          \
        _Pragma("unroll")                                                   \
        for (int i_ = 0; i_ < 4; ++i_)                                      \
          ob_[(size_t)(n0_ + i_) * T_DIM] = al_ * bf2f(fv_[i_]) + om_ * an_[i_]; \
      }                                                                     \
    }                                                                       \
  } while (0)

  // ---- pipelined tile loop: 2 tiles per iteration, static buffers/regs ----
  #pragma unroll 1
  for (int jj = 0; jj < NT; jj += 2) {
    ISSUE(jj + 1, rb);          // next tile's loads in flight first
    COMMIT(ra, S0);             // commit current (ra landed during prev COMPUTE)
    __syncthreads();            // staging of S0 visible
    COMPUTE(S0, jj);            // rb loads + blend stores stream during this

    if (jj + 2 < NT) ISSUE(jj + 2, ra);
    COMMIT(rb, S1);
    __syncthreads();            // staging of S1 visible
    COMPUTE(S1, jj + 1);
  }
#undef ISSUE
#undef COMMIT
#undef COMPUTE
}

extern "C" void kernel_launch(void* const* d_in, const int* in_sizes, int n_in,
                              void* d_out, int out_size, void* d_ws, size_t ws_size,
                              hipStream_t stream) {
  const float* features = (const float*)d_in[0];
  const float* spk      = (const float*)d_in[1];
  const float* Wsp      = (const float*)d_in[2];
  const float* bsp      = (const float*)d_in[3];
  const float* Wv       = (const float*)d_in[4];
  const float* bv       = (const float*)d_in[5];
  const float* Wo       = (const float*)d_in[6];
  const float* bo       = (const float*)d_in[7];
  const float* gma      = (const float*)d_in[8];
  const float* bta      = (const float*)d_in[9];
  const float* Wg1      = (const float*)d_in[10];
  const float* bg1      = (const float*)d_in[11];
  const float* Wg2      = (const float*)d_in[12];
  const float* bg2      = (const float*)d_in[13];
  float* out = (float*)d_out;

  unsigned short* w1fx = (unsigned short*)d_ws;   // 512x512 bf16 = 512 KB

  conv_kernel<<<128, 512, 0, stream>>>(Wg1, w1fx);
  main_kernel<<<256, 512, 0, stream>>>(features, w1fx, spk, Wsp, bsp, Wv, bv,
                                       Wo, bo, gma, bta, Wg1, bg1, Wg2, bg2, out);
}

// Round 5
// 357.319 us; speedup vs baseline: 1.1992x; 1.0143x over previous
//
#include <hip/hip_runtime.h>

// SpeakerCrossAttention on MI355X (gfx950) — v5: two-kernel split.
//   prep  : per-batch chain (attn_n, bias_b) + W1f->bf16      (tiny)
//   alpha : h = F^T@W1f^T (bf16 MFMA), alpha = sigmoid(relu(h+bias)@wg2+bg2)
//           read-only stream of features, writes 512KB of alpha
//   blend : out = alpha*f + (1-alpha)*attn_n   pure f32x4 stream
// v4/v3's register-staged fused pipeline failed (compiler sinks prefetch
// loads, VGPR cap at 128); split kernels have predictable BW behavior.
// Also: XOR bank swizzle on the LDS tile (v1 had 8-way read conflicts,
// 1.26e7 conflict cycles/dispatch from KST=520).

typedef __attribute__((ext_vector_type(8))) short short8;     // 8 bf16 = 16B
typedef __attribute__((ext_vector_type(4))) unsigned short ushort4v;
typedef __attribute__((ext_vector_type(4))) float f32x4;

#define T_DIM 8192
#define D_DIM 512

__device__ __forceinline__ unsigned short f2bf(float x) {  // RTNE f32 -> bf16
  unsigned u = __builtin_bit_cast(unsigned, x);
  u = (u + 0x7fffu + ((u >> 16) & 1u)) >> 16;
  return (unsigned short)u;
}

// ---------------- prep kernel (v1-verified) ----------------
__global__ __launch_bounds__(512) void prep_kernel(
    const float* __restrict__ spk_in, const float* __restrict__ Wsp,
    const float* __restrict__ bsp,    const float* __restrict__ Wv,
    const float* __restrict__ bv,     const float* __restrict__ Wo,
    const float* __restrict__ bo,     const float* __restrict__ gma,
    const float* __restrict__ bta,    const float* __restrict__ Wg1,
    const float* __restrict__ bg1,
    float* __restrict__ attnn, float* __restrict__ biasb,
    unsigned short* __restrict__ w1fx)
{
  int tid = threadIdx.x;
  int blk = blockIdx.x;

  if (blk >= 16) {                    // ---- W1f -> bf16 ----
    int base = (blk - 16) * 2048 + tid;
    #pragma unroll
    for (int i = 0; i < 4; ++i) {
      int idx = base + i * 512;       // 128 blocks * 512 thr * 4 = 512*512
      int n = idx >> 9, k = idx & 511;
      w1fx[idx] = f2bf(Wg1[n * 1024 + k]);
    }
    return;
  }

  int b = blk;
  __shared__ __attribute__((aligned(16))) float s_spk[256];
  __shared__ __attribute__((aligned(16))) float s_x[512];
  __shared__ __attribute__((aligned(16))) float s_y[512];
  __shared__ float red[512];

  float se = (tid < 256) ? spk_in[b * 256 + tid] : 0.f;
  red[tid] = se * se;
  __syncthreads();
  for (int s = 256; s > 0; s >>= 1) {
    if (tid < s) red[tid] += red[tid + s];
    __syncthreads();
  }
  float scale = 1.f / fmaxf(sqrtf(red[0]), 1e-12f);
  if (tid < 256) s_spk[tid] = se * scale;
  __syncthreads();

  {
    const float* wr = Wsp + (size_t)tid * 256;
    f32x4 a4 = {0.f, 0.f, 0.f, 0.f};
    #pragma unroll 8
    for (int s2 = 0; s2 < 256; s2 += 4)
      a4 += (*(const f32x4*)(wr + s2)) * (*(const f32x4*)(s_spk + s2));
    s_x[tid] = a4[0] + a4[1] + a4[2] + a4[3] + bsp[tid];
  }
  __syncthreads();

  {
    const float* wr = Wv + (size_t)tid * 512;
    f32x4 a4 = {0.f, 0.f, 0.f, 0.f};
    #pragma unroll 8
    for (int s2 = 0; s2 < 512; s2 += 4)
      a4 += (*(const f32x4*)(wr + s2)) * (*(const f32x4*)(s_x + s2));
    s_y[tid] = a4[0] + a4[1] + a4[2] + a4[3] + bv[tid];
  }
  __syncthreads();

  float attnv;
  {
    const float* wr = Wo + (size_t)tid * 512;
    f32x4 a4 = {0.f, 0.f, 0.f, 0.f};
    #pragma unroll 8
    for (int s2 = 0; s2 < 512; s2 += 4)
      a4 += (*(const f32x4*)(wr + s2)) * (*(const f32x4*)(s_y + s2));
    attnv = a4[0] + a4[1] + a4[2] + a4[3] + bo[tid];
  }

  red[tid] = attnv;
  __syncthreads();
  for (int s = 256; s > 0; s >>= 1) {
    if (tid < s) red[tid] += red[tid + s];
    __syncthreads();
  }
  float mu = red[0] * (1.f / 512.f);
  __syncthreads();
  float dv = attnv - mu;
  red[tid] = dv * dv;
  __syncthreads();
  for (int s = 256; s > 0; s >>= 1) {
    if (tid < s) red[tid] += red[tid + s];
    __syncthreads();
  }
  float var = red[0] * (1.f / 512.f);
  float an = dv * rsqrtf(var + 1e-5f) * gma[tid] + bta[tid];
  s_x[tid] = an;
  attnn[b * 512 + tid] = an;
  __syncthreads();

  {
    const float* wr = Wg1 + (size_t)tid * 1024 + 512;
    f32x4 a4 = {0.f, 0.f, 0.f, 0.f};
    #pragma unroll 8
    for (int s2 = 0; s2 < 512; s2 += 4)
      a4 += (*(const f32x4*)(wr + s2)) * (*(const f32x4*)(s_x + s2));
    biasb[b * 512 + tid] = a4[0] + a4[1] + a4[2] + a4[3] + bg1[tid];
  }
}

// ---------------- alpha kernel ----------------
// block = (b, t-tile of 64). 512 thr / 8 waves. wave w: n in [64w, 64w+64).
__global__ __launch_bounds__(512) void alpha_kernel(
    const float* __restrict__ feat, const unsigned short* __restrict__ w1fx,
    const float* __restrict__ biasb, const float* __restrict__ wg2p,
    const float* __restrict__ bg2p,  float* __restrict__ alpha_out)
{
  __shared__ __attribute__((aligned(16))) unsigned short S[64 * 512]; // 64KB swizzled
  __shared__ __attribute__((aligned(16))) float s_bias[512];
  __shared__ __attribute__((aligned(16))) float s_wg2[512];
  __shared__ float s_gpart[8 * 64];

  int tid = threadIdx.x;
  int b  = blockIdx.x >> 7;
  int t0 = (blockIdx.x & 127) << 6;
  const float* fb = feat + (size_t)b * D_DIM * T_DIM + t0;
  char* Sb = (char*)S;

  // ---- stage: thread (mt, mk) loads 4t x 16k; all 16 loads issued first ----
  int mt = tid & 15, mk = tid >> 4;      // mk 0..31
  int tt = mt * 4;

  f32x4 r[16];
  #pragma unroll
  for (int it = 0; it < 2; ++it) {
    int k0 = mk * 8 + it * 256;
    #pragma unroll
    for (int q = 0; q < 8; ++q)
      r[it * 8 + q] = __builtin_nontemporal_load(
          (const f32x4*)(fb + (size_t)(k0 + q) * T_DIM + tt));
  }
  s_bias[tid] = biasb[b * 512 + tid];
  s_wg2[tid]  = wg2p[tid];
  __builtin_amdgcn_sched_barrier(0);     // keep all loads issued before commits

  #pragma unroll
  for (int it = 0; it < 2; ++it) {
    int kbyte = (mk * 8 + it * 256) * 2;
    #pragma unroll
    for (int i = 0; i < 4; ++i) {
      short8 wv;
      #pragma unroll
      for (int q = 0; q < 8; ++q)
        wv[q] = (short)f2bf(r[it * 8 + q][i]);
      int row = tt + i;
      int byte = (row << 10) + kbyte;
      byte ^= (row & 7) << 4;            // bank swizzle (st_16-style)
      *(short8*)(Sb + byte) = wv;        // ds_write_b128
    }
  }
  __syncthreads();

  // ---- GEMM: h^T = W1f * F^T (v1-verified mapping) ----
  int l = tid & 63, w = tid >> 6;
  int g = l >> 4, c = l & 15;
  int n0w = w * 64;
  const unsigned short* ap0 = w1fx + (size_t)(n0w + c) * 512 + g * 8;
  int xsw = (c & 7) << 4;
  int bb0 = (c << 10) + g * 16;          // row c, kbyte g*16

  f32x4 acc[4][4];
  #pragma unroll
  for (int i = 0; i < 4; ++i)
    #pragma unroll
    for (int j = 0; j < 4; ++j)
      acc[i][j] = (f32x4){0.f, 0.f, 0.f, 0.f};

  #pragma unroll 2
  for (int kk = 0; kk < 16; ++kk) {
    short8 af[4], bf[4];
    #pragma unroll
    for (int ni = 0; ni < 4; ++ni)
      af[ni] = *(const short8*)(ap0 + ni * (16 * 512) + kk * 32);
    #pragma unroll
    for (int tg = 0; tg < 4; ++tg)
      bf[tg] = *(const short8*)(Sb + ((bb0 + tg * 16384 + kk * 64) ^ xsw));
    #pragma unroll
    for (int ni = 0; ni < 4; ++ni)
      #pragma unroll
      for (int tg = 0; tg < 4; ++tg)
        acc[ni][tg] = __builtin_amdgcn_mfma_f32_16x16x32_bf16(
            af[ni], bf[tg], acc[ni][tg], 0, 0, 0);
  }
  // lane l, reg rr of acc[ni][tg]: h[n = n0w+16ni+4g+rr][t = 16tg+c]

  float p0 = 0.f, p1 = 0.f, p2 = 0.f, p3 = 0.f;
  #pragma unroll
  for (int ni = 0; ni < 4; ++ni) {
    #pragma unroll
    for (int rr = 0; rr < 4; ++rr) {
      int n = n0w + 16 * ni + 4 * g + rr;
      float bb = s_bias[n], ww = s_wg2[n];
      p0 += fmaxf(acc[ni][0][rr] + bb, 0.f) * ww;
      p1 += fmaxf(acc[ni][1][rr] + bb, 0.f) * ww;
      p2 += fmaxf(acc[ni][2][rr] + bb, 0.f) * ww;
      p3 += fmaxf(acc[ni][3][rr] + bb, 0.f) * ww;
    }
  }
  p0 += __shfl_xor(p0, 16); p0 += __shfl_xor(p0, 32);
  p1 += __shfl_xor(p1, 16); p1 += __shfl_xor(p1, 32);
  p2 += __shfl_xor(p2, 16); p2 += __shfl_xor(p2, 32);
  p3 += __shfl_xor(p3, 16); p3 += __shfl_xor(p3, 32);
  if (l < 16) {
    s_gpart[w * 64 +  0 + l] = p0;
    s_gpart[w * 64 + 16 + l] = p1;
    s_gpart[w * 64 + 32 + l] = p2;
    s_gpart[w * 64 + 48 + l] = p3;
  }
  __syncthreads();
  if (tid < 64) {
    float gs = bg2p[0];
    #pragma unroll
    for (int w2 = 0; w2 < 8; ++w2) gs += s_gpart[w2 * 64 + tid];
    alpha_out[(size_t)b * T_DIM + t0 + tid] = 1.f / (1.f + expf(-gs));
  }
}

// ---------------- blend kernel: pure stream ----------------
__global__ __launch_bounds__(256) void blend_kernel(
    const float* __restrict__ feat,  const float* __restrict__ alpha,
    const float* __restrict__ attnn, float* __restrict__ out)
{
  int gtid = blockIdx.x * 256 + threadIdx.x;
  const int stride = 2048 * 256;          // total threads
  #pragma unroll 1
  for (int i4 = gtid; i4 < 16777216; i4 += stride) {   // 67.1M elems / 4
    size_t flat = (size_t)i4 * 4;
    int t  = (int)(flat & 8191);
    int bd = (int)(flat >> 13);           // = b*512 + d
    int b  = bd >> 9;
    f32x4 f = __builtin_nontemporal_load((const f32x4*)(feat + flat));
    f32x4 a = *(const f32x4*)(alpha + ((size_t)b << 13) + t);
    float an = attnn[bd];
    f32x4 o;
    #pragma unroll
    for (int j = 0; j < 4; ++j)
      o[j] = a[j] * f[j] + (1.f - a[j]) * an;
    __builtin_nontemporal_store(o, (f32x4*)(out + flat));
  }
}

extern "C" void kernel_launch(void* const* d_in, const int* in_sizes, int n_in,
                              void* d_out, int out_size, void* d_ws, size_t ws_size,
                              hipStream_t stream) {
  const float* features = (const float*)d_in[0];
  const float* spk      = (const float*)d_in[1];
  const float* Wsp      = (const float*)d_in[2];
  const float* bsp      = (const float*)d_in[3];
  const float* Wv       = (const float*)d_in[4];
  const float* bv       = (const float*)d_in[5];
  const float* Wo       = (const float*)d_in[6];
  const float* bo       = (const float*)d_in[7];
  const float* gma      = (const float*)d_in[8];
  const float* bta      = (const float*)d_in[9];
  const float* Wg1      = (const float*)d_in[10];
  const float* bg1      = (const float*)d_in[11];
  const float* Wg2      = (const float*)d_in[12];
  const float* bg2      = (const float*)d_in[13];
  float* out = (float*)d_out;

  // ws: attnn[8192] f32 | biasb[8192] f32 | alpha[131072] f32 | w1fx[262144] bf16
  float* attnn = (float*)d_ws;
  float* biasb = attnn + 8192;
  float* alpha = biasb + 8192;
  unsigned short* w1fx = (unsigned short*)(alpha + 131072);

  prep_kernel<<<144, 512, 0, stream>>>(spk, Wsp, bsp, Wv, bv, Wo, bo, gma, bta,
                                       Wg1, bg1, attnn, biasb, w1fx);
  alpha_kernel<<<2048, 512, 0, stream>>>(features, w1fx, biasb, Wg2, bg2, alpha);
  blend_kernel<<<2048, 256, 0, stream>>>(features, alpha, attnn, out);
}